// Round 6
// baseline (362.255 us; speedup 1.0000x reference)
//
#include <hip/hip_runtime.h>
#include <math.h>

#define T_DIM 4096
#define D_DIM 256
#define K_NUM 1024
#define B_NUM 16
#define N_TOT (B_NUM * T_DIM)   // 65536
#define EPS_FLAG 0.2f

typedef _Float16 half8 __attribute__((ext_vector_type(8)));
typedef float f32x4 __attribute__((ext_vector_type(4)));

// ---------------- ws layout (bytes) ----------------
#define WS_FLAGCNT 0
#define WS_LOSS 4
#define WS_HIST 64
#define WS_E2 4352
#define WS_QIDX 8704            // 256 KB
#define WS_FLAGLIST 270848      // 256 KB
#define WS_ESWZ 540672          // 512 KB: fp16 embed, fragment-swizzled (16B aligned)

// ---------------- kernel: |e_k|^2 (exact fp32) ----------------
__global__ __launch_bounds__(256) void e2_kernel(const float* __restrict__ embed,
                                                 float* __restrict__ e2) {
    const int wave = threadIdx.x >> 6;
    const int lane = threadIdx.x & 63;
    const int k = blockIdx.x * 4 + wave;
    const float4* row = (const float4*)(embed + (size_t)k * D_DIM);
    float4 v = row[lane];
    float s = v.x * v.x + v.y * v.y + v.z * v.z + v.w * v.w;
    #pragma unroll
    for (int off = 32; off; off >>= 1) s += __shfl_down(s, off);
    if (lane == 0) e2[k] = s;
}

// ---------------- kernel: convert embed to fp16, fragment-swizzled ----------------
// 16-col chunk c (8192 B): [k 0..7: 1KB each]. lane l -> 16 B = 8 fp16:
// col=c*16+(l&15), d=k*32+(l>>4)*8+j  (m89/m91 B-fragment layout)
__global__ __launch_bounds__(256) void prep_eswz_kernel(const float* __restrict__ embed,
                                                        unsigned char* __restrict__ eswz) {
    const int tau = blockIdx.x * 256 + threadIdx.x;   // 0..32767
    const int c = tau >> 9;
    const int k = (tau >> 6) & 7;
    const int l = tau & 63;
    const int col = c * 16 + (l & 15);
    const int d0 = k * 32 + ((l >> 4) << 3);
    const float* src = embed + (size_t)col * D_DIM + d0;
    half8 h;
    #pragma unroll
    for (int j = 0; j < 8; ++j) h[j] = (_Float16)src[j];
    *(half8*)(eswz + (size_t)c * 8192 + k * 1024 + l * 16) = h;
}

// ---------------- kernel: fp16 MFMA distance + top-2 argmin (barrier-free K-loop) ----------------
// 512 blocks x 256 thr. Block: 128 rows; wave: 32 rows (2 A-frags), loops 64 chunks of
// 16 cols. B fragments loaded DIRECTLY from global (L2-resident 512 KB), register dbuf.
__global__ __launch_bounds__(256, 3) void argmin_mfma_kernel(
    const float* __restrict__ x, const unsigned char* __restrict__ eswz,
    const float* __restrict__ e2, int* __restrict__ qidx,
    int* __restrict__ flagcnt, int* __restrict__ flaglist)
{
    __shared__ float e2s[K_NUM];

    const int tid = threadIdx.x;
    const int w = tid >> 6;
    const int l = tid & 63;
    const int rb = blockIdx.x * 128;
    const int b = rb >> 12;
    const float* xb = x + (size_t)b * (D_DIM * T_DIM);
    const half8* __restrict__ Bbase = (const half8*)eswz;   // [chunk*512 + k*64 + lane]

    for (int i = tid; i < K_NUM; i += 256) e2s[i] = e2[i];

    // A fragments (fp16): 2 row-frags x 8 ksteps = 64 VGPR
    half8 Ah[2][8];
    #pragma unroll
    for (int f = 0; f < 2; ++f) {
        const int row = rb + w * 32 + f * 16 + (l & 15);
        const int t = row & (T_DIM - 1);
        const float* xp = xb + t;
        #pragma unroll
        for (int k = 0; k < 8; ++k) {
            const int d0 = k * 32 + ((l >> 4) << 3);
            half8 h;
            #pragma unroll
            for (int j = 0; j < 8; ++j) h[j] = (_Float16)xp[(size_t)(d0 + j) * T_DIM];
            Ah[f][k] = h;
        }
    }
    __syncthreads();   // e2s ready (only barrier in the kernel)

    float bestv[8], secv[8];
    int   besti[8];
    #pragma unroll
    for (int s = 0; s < 8; ++s) { bestv[s] = 3.4e38f; secv[s] = 3.4e38f; besti[s] = 0x7FFFFFFF; }

    // register double-buffer for B fragments
    half8 Bp[8];
    #pragma unroll
    for (int k = 0; k < 8; ++k) Bp[k] = Bbase[k * 64 + l];

    for (int c = 0; c < 64; ++c) {
        half8 Bc[8];
        #pragma unroll
        for (int k = 0; k < 8; ++k) Bc[k] = Bp[k];
        if (c + 1 < 64) {
            const int nb = (c + 1) * 512 + l;
            #pragma unroll
            for (int k = 0; k < 8; ++k) Bp[k] = Bbase[nb + k * 64];
        }

        f32x4 a0 = {0.f,0.f,0.f,0.f}, a1 = {0.f,0.f,0.f,0.f};
        #pragma unroll
        for (int k = 0; k < 8; ++k) {
            a0 = __builtin_amdgcn_mfma_f32_16x16x32_f16(Ah[0][k], Bc[k], a0, 0, 0, 0);
            a1 = __builtin_amdgcn_mfma_f32_16x16x32_f16(Ah[1][k], Bc[k], a1, 0, 0, 0);
        }

        const int col = c * 16 + (l & 15);
        const float e2c = e2s[col];
        #pragma unroll
        for (int r = 0; r < 4; ++r) {
            float s0 = fmaf(-2.f, a0[r], e2c);
            bool u0 = s0 < bestv[r];
            secv[r] = fminf(secv[r], u0 ? bestv[r] : s0);
            bestv[r] = u0 ? s0 : bestv[r];
            besti[r] = u0 ? col : besti[r];
            float s1 = fmaf(-2.f, a1[r], e2c);
            bool u1 = s1 < bestv[4 + r];
            secv[4 + r] = fminf(secv[4 + r], u1 ? bestv[4 + r] : s1);
            bestv[4 + r] = u1 ? s1 : bestv[4 + r];
            besti[4 + r] = u1 ? col : besti[4 + r];
        }
    }

    // merge top-2 across the 16 lanes sharing each row (xor 1,2,4,8 stays in-group)
    #pragma unroll
    for (int slot = 0; slot < 8; ++slot) {
        float bv = bestv[slot], sv = secv[slot];
        int bi = besti[slot];
        #pragma unroll
        for (int d = 1; d < 16; d <<= 1) {
            float ob = __shfl_xor(bv, d);
            int   oi = __shfl_xor(bi, d);
            float os = __shfl_xor(sv, d);
            bool take = (ob < bv) || (ob == bv && oi < bi);
            float loser = take ? bv : ob;
            bv = take ? ob : bv;
            bi = take ? oi : bi;
            sv = fminf(fminf(sv, os), loser);
        }
        if ((l & 15) == 0) {
            const int row = rb + w * 32 + (slot >> 2) * 16 + (l >> 4) * 4 + (slot & 3);
            qidx[row] = bi;
            if (sv - bv < EPS_FLAG) {
                int p = atomicAdd(flagcnt, 1);
                flaglist[p] = row;
            }
        }
    }
}

// ---------------- kernel: exact fp32 re-resolve, ONE flagged row per block ----------------
// grid 2048 blocks (grid-stride). 256 thr: 4 cols/thread, x row staged in LDS.
__global__ __launch_bounds__(256) void cleanup_kernel(
    const float* __restrict__ x, const float* __restrict__ embed,
    const float* __restrict__ e2, const int* __restrict__ flagcnt,
    const int* __restrict__ flaglist, int* __restrict__ qidx)
{
    __shared__ float xs[256];
    __shared__ float rv[4];
    __shared__ int   rix[4];
    const int tid = threadIdx.x;
    const int w = tid >> 6, l = tid & 63;
    int cnt = flagcnt[0];
    if (cnt > N_TOT) cnt = N_TOT;
    for (int it = blockIdx.x; it < cnt; it += gridDim.x) {
        const int row = flaglist[it];
        const int b = row >> 12, t = row & (T_DIM - 1);
        __syncthreads();   // protect xs reuse across iterations
        xs[tid] = x[(size_t)b * (D_DIM * T_DIM) + (size_t)tid * T_DIM + t];
        __syncthreads();
        float best = 3.4e38f; int bi = 0x7FFFFFFF;
        #pragma unroll
        for (int q = 0; q < 4; ++q) {
            const int c = q * 256 + tid;
            const float4* ep = (const float4*)(embed + (size_t)c * D_DIM);
            float acc = 0.f;
            #pragma unroll 8
            for (int d4 = 0; d4 < 64; ++d4) {
                const float4 ev = ep[d4];
                const float4 xv = *(const float4*)&xs[d4 * 4];
                acc += ev.x * xv.x + ev.y * xv.y + ev.z * xv.z + ev.w * xv.w;
            }
            const float s = e2[c] - 2.f * acc;
            if (s < best || (s == best && c < bi)) { best = s; bi = c; }
        }
        #pragma unroll
        for (int d = 32; d; d >>= 1) {
            float ov = __shfl_down(best, d); int oi = __shfl_down(bi, d);
            if (ov < best || (ov == best && oi < bi)) { best = ov; bi = oi; }
        }
        if (l == 0) { rv[w] = best; rix[w] = bi; }
        __syncthreads();
        if (tid == 0) {
            float v = rv[0]; int i = rix[0];
            #pragma unroll
            for (int w2 = 1; w2 < 4; ++w2) {
                if (rv[w2] < v || (rv[w2] == v && rix[w2] < i)) { v = rv[w2]; i = rix[w2]; }
            }
            qidx[row] = i;
        }
    }
}

// ---------------- kernel: gather z_q + loss + histogram (LDS-free) ----------------
__global__ __launch_bounds__(256) void gather_kernel(
    const float* __restrict__ x, const float* __restrict__ embed,
    const int* __restrict__ qidx, float* __restrict__ out,
    float* __restrict__ loss_sum, int* __restrict__ hist)
{
    const int tid = threadIdx.x;
    const int n = blockIdx.x * 256 + tid;
    const int b = n >> 12, t = n & (T_DIM - 1);
    const int d0 = blockIdx.y * 64;
    const int idx = qidx[n];
    if (blockIdx.y == 0) atomicAdd(&hist[idx], 1);

    const float4* ep = (const float4*)(embed + (size_t)idx * D_DIM + d0);
    const float* xp = x + (size_t)b * (D_DIM * T_DIM) + (size_t)d0 * T_DIM + t;
    float*       op = out + (size_t)b * (D_DIM * T_DIM) + (size_t)d0 * T_DIM + t;

    float local = 0.f;
    #pragma unroll 4
    for (int i = 0; i < 16; ++i) {
        const float4 ev = ep[i];
        const size_t dd = (size_t)i * 4;
        float xv0 = xp[(dd + 0) * T_DIM];
        float xv1 = xp[(dd + 1) * T_DIM];
        float xv2 = xp[(dd + 2) * T_DIM];
        float xv3 = xp[(dd + 3) * T_DIM];
        op[(dd + 0) * T_DIM] = ev.x;
        op[(dd + 1) * T_DIM] = ev.y;
        op[(dd + 2) * T_DIM] = ev.z;
        op[(dd + 3) * T_DIM] = ev.w;
        float f0 = ev.x - xv0, f1 = ev.y - xv1, f2 = ev.z - xv2, f3 = ev.w - xv3;
        local = fmaf(f0, f0, local);
        local = fmaf(f1, f1, local);
        local = fmaf(f2, f2, local);
        local = fmaf(f3, f3, local);
    }
    #pragma unroll
    for (int off = 32; off; off >>= 1) local += __shfl_down(local, off);
    __shared__ float ls[4];
    if ((tid & 63) == 0) ls[tid >> 6] = local;
    __syncthreads();
    if (tid == 0) atomicAdd(loss_sum, ls[0] + ls[1] + ls[2] + ls[3]);
}

// ---------------- kernel: entropy / finalize ----------------
__global__ __launch_bounds__(256) void finalize_kernel(
    const int* __restrict__ hist, const float* __restrict__ loss_sum,
    float* __restrict__ out)
{
    const int tid = threadIdx.x;
    float acc = 0.f;
    #pragma unroll
    for (int i = tid; i < K_NUM; i += 256) {
        const float p = (float)hist[i] * (1.f / (float)N_TOT);
        acc += p * logf(p + 1e-10f);
    }
    #pragma unroll
    for (int off = 32; off; off >>= 1) acc += __shfl_down(acc, off);
    __shared__ float ls[4];
    if ((tid & 63) == 0) ls[tid >> 6] = acc;
    __syncthreads();
    if (tid == 0) {
        const float H = -(ls[0] + ls[1] + ls[2] + ls[3]);
        const size_t base = (size_t)N_TOT * D_DIM;   // 16777216
        out[base] = 1.25f * loss_sum[0] * (1.f / 16777216.f);
        const float kld = (float)(6.931471805599453 * 4096.0);  // log(1024)*T
        #pragma unroll
        for (int i = 0; i < 16; ++i) out[base + 1 + i] = kld;
        out[base + 17] = expf(H);
    }
}

extern "C" void kernel_launch(void* const* d_in, const int* in_sizes, int n_in,
                              void* d_out, int out_size, void* d_ws, size_t ws_size,
                              hipStream_t stream)
{
    const float* x     = (const float*)d_in[0];   // (16, 256, 4096) f32
    const float* embed = (const float*)d_in[1];   // (1024, 256) f32
    float* out = (float*)d_out;

    char* ws = (char*)d_ws;
    int*   flagcnt  = (int*)(ws + WS_FLAGCNT);
    float* loss_sum = (float*)(ws + WS_LOSS);
    int*   hist     = (int*)(ws + WS_HIST);
    float* e2       = (float*)(ws + WS_E2);
    int*   qidx     = (int*)(ws + WS_QIDX);
    int*   flaglist = (int*)(ws + WS_FLAGLIST);
    unsigned char* eswz = (unsigned char*)(ws + WS_ESWZ);

    hipMemsetAsync(ws, 0, 4160, stream);  // flagcnt + loss_sum + hist

    e2_kernel<<<K_NUM / 4, 256, 0, stream>>>(embed, e2);
    prep_eswz_kernel<<<128, 256, 0, stream>>>(embed, eswz);
    argmin_mfma_kernel<<<N_TOT / 128, 256, 0, stream>>>(x, eswz, e2, qidx, flagcnt, flaglist);
    cleanup_kernel<<<2048, 256, 0, stream>>>(x, embed, e2, flagcnt, flaglist, qidx);
    gather_kernel<<<dim3(N_TOT / 256, 4), 256, 0, stream>>>(x, embed, qidx, out, loss_sum, hist);
    finalize_kernel<<<1, 256, 0, stream>>>(hist, loss_sum, out);
}

// Round 7
// 336.944 us; speedup vs baseline: 1.0751x; 1.0751x over previous
//
#include <hip/hip_runtime.h>
#include <math.h>

#define T_DIM 4096
#define D_DIM 256
#define K_NUM 1024
#define B_NUM 16
#define N_TOT (B_NUM * T_DIM)   // 65536
#define EPS_FLAG 0.12f

typedef _Float16 half8 __attribute__((ext_vector_type(8)));
typedef float f32x4 __attribute__((ext_vector_type(4)));

// ---------------- ws layout (bytes) ----------------
#define WS_FLAGCNT 0
#define WS_LOSS 4
#define WS_HIST 64
#define WS_E2 4352
#define WS_QIDX 8704            // 256 KB
#define WS_FLAGLIST 270848      // 256 KB
#define WS_ESWZ 540672          // 512 KB: fp16 embed, fragment-swizzled (16B aligned)

// async 16B global->LDS; LDS dest = wave-uniform base + lane*16.
__device__ inline void gl_lds16(const void* g, void* l) {
    __builtin_amdgcn_global_load_lds(
        (const __attribute__((address_space(1))) unsigned int*)g,
        (__attribute__((address_space(3))) unsigned int*)l, 16, 0, 0);
}

// ---------------- kernel: |e_k|^2 (exact fp32) ----------------
__global__ __launch_bounds__(256) void e2_kernel(const float* __restrict__ embed,
                                                 float* __restrict__ e2) {
    const int wave = threadIdx.x >> 6;
    const int lane = threadIdx.x & 63;
    const int k = blockIdx.x * 4 + wave;
    const float4* row = (const float4*)(embed + (size_t)k * D_DIM);
    float4 v = row[lane];
    float s = v.x * v.x + v.y * v.y + v.z * v.z + v.w * v.w;
    #pragma unroll
    for (int off = 32; off; off >>= 1) s += __shfl_down(s, off);
    if (lane == 0) e2[k] = s;
}

// ---------------- kernel: convert embed to fp16, fragment-swizzled ----------------
// 16-col chunk c (8192 B): [k 0..7: 1KB each]. lane l -> 16 B = 8 fp16:
// col=c*16+(l&15), d=k*32+(l>>4)*8+j  (m89/m91 B-fragment layout)
__global__ __launch_bounds__(256) void prep_eswz_kernel(const float* __restrict__ embed,
                                                        unsigned char* __restrict__ eswz) {
    const int tau = blockIdx.x * 256 + threadIdx.x;   // 0..32767
    const int c = tau >> 9;
    const int k = (tau >> 6) & 7;
    const int l = tau & 63;
    const int col = c * 16 + (l & 15);
    const int d0 = k * 32 + ((l >> 4) << 3);
    const float* src = embed + (size_t)col * D_DIM + d0;
    half8 h;
    #pragma unroll
    for (int j = 0; j < 8; ++j) h[j] = (_Float16)src[j];
    *(half8*)(eswz + (size_t)c * 8192 + k * 1024 + l * 16) = h;
}

// ---------------- kernel: fp16 MFMA distance + top-2 argmin ----------------
// 512 blocks x 256 thr. Block: 128 rows x all 1024 cols; wave: 32 rows (2 A-frags).
// 32 chunks of 32 cols (2 col-frags); async global_load_lds dbuf 2x16KB; 1 barrier/chunk.
__global__ __launch_bounds__(256, 4) void argmin_mfma_kernel(
    const float* __restrict__ x, const unsigned char* __restrict__ eswz,
    const float* __restrict__ e2, int* __restrict__ qidx,
    int* __restrict__ flagcnt, int* __restrict__ flaglist)
{
    __shared__ __align__(16) unsigned char bbuf[2][16384];
    __shared__ float e2s[K_NUM];

    const int tid = threadIdx.x;
    const int w = tid >> 6;
    const int l = tid & 63;
    const int rb = blockIdx.x * 128;
    const int b = rb >> 12;
    const float* xb = x + (size_t)b * (D_DIM * T_DIM);

    {   // issue chunk 0 (overlaps A conversion)
        const unsigned char* src = eswz + (size_t)tid * 16;
        #pragma unroll
        for (int r = 0; r < 4; ++r) gl_lds16(src + r * 4096, &bbuf[0][tid * 16 + r * 4096]);
    }
    for (int i = tid; i < K_NUM; i += 256) e2s[i] = e2[i];

    // A fragments (fp16): 2 row-frags x 8 ksteps = 64 VGPR
    half8 Ah[2][8];
    #pragma unroll
    for (int f = 0; f < 2; ++f) {
        const int row = rb + w * 32 + f * 16 + (l & 15);
        const int t = row & (T_DIM - 1);
        const float* xp = xb + t;
        #pragma unroll
        for (int k = 0; k < 8; ++k) {
            const int d0 = k * 32 + ((l >> 4) << 3);
            half8 h;
            #pragma unroll
            for (int j = 0; j < 8; ++j) h[j] = (_Float16)xp[(size_t)(d0 + j) * T_DIM];
            Ah[f][k] = h;
        }
    }
    __syncthreads();   // drains chunk-0 loads + e2s

    float bestv[8], secv[8];
    int   besti[8];
    #pragma unroll
    for (int s = 0; s < 8; ++s) { bestv[s] = 3.4e38f; secv[s] = 3.4e38f; besti[s] = 0x7FFFFFFF; }

    for (int g = 0; g < 32; ++g) {
        if (g + 1 < 32) {   // async prefetch next chunk into the other buffer
            const unsigned char* src = eswz + (size_t)(g + 1) * 16384 + (size_t)tid * 16;
            unsigned char* dst = &bbuf[(g + 1) & 1][tid * 16];
            #pragma unroll
            for (int r = 0; r < 4; ++r) gl_lds16(src + r * 4096, dst + r * 4096);
        }
        const unsigned char* bb = bbuf[g & 1];

        f32x4 a00 = {0.f,0.f,0.f,0.f}, a01 = {0.f,0.f,0.f,0.f};
        f32x4 a10 = {0.f,0.f,0.f,0.f}, a11 = {0.f,0.f,0.f,0.f};
        #pragma unroll
        for (int k = 0; k < 8; ++k) {
            half8 b0 = *(const half8*)(bb + k * 1024 + l * 16);           // cols g*32..+16
            half8 b1 = *(const half8*)(bb + 8192 + k * 1024 + l * 16);    // cols +16..+32
            a00 = __builtin_amdgcn_mfma_f32_16x16x32_f16(Ah[0][k], b0, a00, 0, 0, 0);
            a10 = __builtin_amdgcn_mfma_f32_16x16x32_f16(Ah[1][k], b0, a10, 0, 0, 0);
            a01 = __builtin_amdgcn_mfma_f32_16x16x32_f16(Ah[0][k], b1, a01, 0, 0, 0);
            a11 = __builtin_amdgcn_mfma_f32_16x16x32_f16(Ah[1][k], b1, a11, 0, 0, 0);
        }

        const int col0 = g * 32 + (l & 15);
        const float e2a = e2s[col0];
        const float e2b = e2s[col0 + 16];
        #pragma unroll
        for (int f = 0; f < 2; ++f) {
            const f32x4 accA = f ? a10 : a00;
            const f32x4 accB = f ? a11 : a01;
            #pragma unroll
            for (int r = 0; r < 4; ++r) {
                const int s = f * 4 + r;
                float sA = fmaf(-2.f, accA[r], e2a);
                float sB = fmaf(-2.f, accB[r], e2b);
                bool swp = sB < sA;
                float lo = swp ? sB : sA;
                float hi = swp ? sA : sB;
                int   li = swp ? col0 + 16 : col0;
                bool upd = lo < bestv[s];
                float mx = upd ? bestv[s] : lo;
                bestv[s] = upd ? lo : bestv[s];
                besti[s] = upd ? li : besti[s];
                secv[s] = fminf(secv[s], fminf(mx, hi));
            }
        }
        __syncthreads();   // drains my prefetch; protects both buffers
    }

    // merge top-2 across the 16 lanes sharing each row (xor 1,2,4,8 stays in-group)
    #pragma unroll
    for (int slot = 0; slot < 8; ++slot) {
        float bv = bestv[slot], sv = secv[slot];
        int bi = besti[slot];
        #pragma unroll
        for (int d = 1; d < 16; d <<= 1) {
            float ob = __shfl_xor(bv, d);
            int   oi = __shfl_xor(bi, d);
            float os = __shfl_xor(sv, d);
            bool take = (ob < bv) || (ob == bv && oi < bi);
            float loser = take ? bv : ob;
            bv = take ? ob : bv;
            bi = take ? oi : bi;
            sv = fminf(fminf(sv, os), loser);
        }
        if ((l & 15) == 0) {
            const int row = rb + w * 32 + (slot >> 2) * 16 + (l >> 4) * 4 + (slot & 3);
            qidx[row] = bi;
            if (sv - bv < EPS_FLAG) {
                int p = atomicAdd(flagcnt, 1);
                flaglist[p] = row;
            }
        }
    }
}

// ---------------- kernel: exact fp32 re-resolve, 16 flagged rows per group ----------------
// grid 2048, grid-stride over groups; codebook streamed once per 16 rows (16x reuse).
__global__ __launch_bounds__(256) void cleanup_kernel(
    const float* __restrict__ x, const float* __restrict__ embed,
    const float* __restrict__ e2, const int* __restrict__ flagcnt,
    const int* __restrict__ flaglist, int* __restrict__ qidx)
{
    __shared__ float xs[16][256];
    __shared__ int rows_s[16];
    __shared__ float rv[16][4];
    __shared__ int   rix[16][4];
    const int tid = threadIdx.x;
    int cnt = flagcnt[0];
    if (cnt > N_TOT) cnt = N_TOT;
    const int ngrp = (cnt + 15) >> 4;
    for (int grp = blockIdx.x; grp < ngrp; grp += gridDim.x) {
        __syncthreads();
        if (tid < 16) rows_s[tid] = (grp * 16 + tid < cnt) ? flaglist[grp * 16 + tid] : -1;
        __syncthreads();
        {   // stage 16 x-rows into LDS
            const int j = tid & 15, ch = tid >> 4;
            const int row = rows_s[j];
            if (row >= 0) {
                const int bb = row >> 12, t = row & (T_DIM - 1);
                const float* xp = x + (size_t)bb * (D_DIM * T_DIM) + t;
                #pragma unroll
                for (int i = 0; i < 16; ++i) {
                    const int d = ch * 16 + i;
                    xs[j][d] = xp[(size_t)d * T_DIM];
                }
            }
        }
        __syncthreads();
        float bv[16]; int bix[16];
        #pragma unroll
        for (int j = 0; j < 16; ++j) { bv[j] = 3.4e38f; bix[j] = 0x7FFFFFFF; }
        for (int q = 0; q < 4; ++q) {
            const int c = q * 256 + tid;
            const float4* ep = (const float4*)(embed + (size_t)c * D_DIM);
            float acc[16];
            #pragma unroll
            for (int j = 0; j < 16; ++j) acc[j] = 0.f;
            for (int d4 = 0; d4 < 64; ++d4) {
                const float4 ev = ep[d4];
                #pragma unroll
                for (int j = 0; j < 16; ++j) {
                    const float4 xv = *(const float4*)&xs[j][d4 * 4];
                    acc[j] += ev.x * xv.x + ev.y * xv.y + ev.z * xv.z + ev.w * xv.w;
                }
            }
            const float e2c = e2[c];
            #pragma unroll
            for (int j = 0; j < 16; ++j) {
                float s = e2c - 2.f * acc[j];
                if (s < bv[j] || (s == bv[j] && c < bix[j])) { bv[j] = s; bix[j] = c; }
            }
        }
        const int w = tid >> 6, l = tid & 63;
        #pragma unroll
        for (int j = 0; j < 16; ++j) {
            float v = bv[j]; int i = bix[j];
            #pragma unroll
            for (int d = 32; d; d >>= 1) {
                float ov = __shfl_down(v, d); int oi = __shfl_down(i, d);
                if (ov < v || (ov == v && oi < i)) { v = ov; i = oi; }
            }
            if (l == 0) { rv[j][w] = v; rix[j][w] = i; }
        }
        __syncthreads();
        if (tid < 16 && rows_s[tid] >= 0) {
            float v = rv[tid][0]; int i = rix[tid][0];
            #pragma unroll
            for (int w2 = 1; w2 < 4; ++w2) {
                float ov = rv[tid][w2]; int oi = rix[tid][w2];
                if (ov < v || (ov == v && oi < i)) { v = ov; i = oi; }
            }
            qidx[rows_s[tid]] = i;
        }
    }
}

// ---------------- kernel: gather z_q + loss + histogram (LDS-free) ----------------
__global__ __launch_bounds__(256) void gather_kernel(
    const float* __restrict__ x, const float* __restrict__ embed,
    const int* __restrict__ qidx, float* __restrict__ out,
    float* __restrict__ loss_sum, int* __restrict__ hist)
{
    const int tid = threadIdx.x;
    const int n = blockIdx.x * 256 + tid;
    const int b = n >> 12, t = n & (T_DIM - 1);
    const int d0 = blockIdx.y * 64;
    const int idx = qidx[n];
    if (blockIdx.y == 0) atomicAdd(&hist[idx], 1);

    const float4* ep = (const float4*)(embed + (size_t)idx * D_DIM + d0);
    const float* xp = x + (size_t)b * (D_DIM * T_DIM) + (size_t)d0 * T_DIM + t;
    float*       op = out + (size_t)b * (D_DIM * T_DIM) + (size_t)d0 * T_DIM + t;

    float local = 0.f;
    #pragma unroll 4
    for (int i = 0; i < 16; ++i) {
        const float4 ev = ep[i];
        const size_t dd = (size_t)i * 4;
        float xv0 = xp[(dd + 0) * T_DIM];
        float xv1 = xp[(dd + 1) * T_DIM];
        float xv2 = xp[(dd + 2) * T_DIM];
        float xv3 = xp[(dd + 3) * T_DIM];
        op[(dd + 0) * T_DIM] = ev.x;
        op[(dd + 1) * T_DIM] = ev.y;
        op[(dd + 2) * T_DIM] = ev.z;
        op[(dd + 3) * T_DIM] = ev.w;
        float f0 = ev.x - xv0, f1 = ev.y - xv1, f2 = ev.z - xv2, f3 = ev.w - xv3;
        local = fmaf(f0, f0, local);
        local = fmaf(f1, f1, local);
        local = fmaf(f2, f2, local);
        local = fmaf(f3, f3, local);
    }
    #pragma unroll
    for (int off = 32; off; off >>= 1) local += __shfl_down(local, off);
    __shared__ float ls[4];
    if ((tid & 63) == 0) ls[tid >> 6] = local;
    __syncthreads();
    if (tid == 0) atomicAdd(loss_sum, ls[0] + ls[1] + ls[2] + ls[3]);
}

// ---------------- kernel: entropy / finalize ----------------
__global__ __launch_bounds__(256) void finalize_kernel(
    const int* __restrict__ hist, const float* __restrict__ loss_sum,
    float* __restrict__ out)
{
    const int tid = threadIdx.x;
    float acc = 0.f;
    #pragma unroll
    for (int i = tid; i < K_NUM; i += 256) {
        const float p = (float)hist[i] * (1.f / (float)N_TOT);
        acc += p * logf(p + 1e-10f);
    }
    #pragma unroll
    for (int off = 32; off; off >>= 1) acc += __shfl_down(acc, off);
    __shared__ float ls[4];
    if ((tid & 63) == 0) ls[tid >> 6] = acc;
    __syncthreads();
    if (tid == 0) {
        const float H = -(ls[0] + ls[1] + ls[2] + ls[3]);
        const size_t base = (size_t)N_TOT * D_DIM;   // 16777216
        out[base] = 1.25f * loss_sum[0] * (1.f / 16777216.f);
        const float kld = (float)(6.931471805599453 * 4096.0);  // log(1024)*T
        #pragma unroll
        for (int i = 0; i < 16; ++i) out[base + 1 + i] = kld;
        out[base + 17] = expf(H);
    }
}

extern "C" void kernel_launch(void* const* d_in, const int* in_sizes, int n_in,
                              void* d_out, int out_size, void* d_ws, size_t ws_size,
                              hipStream_t stream)
{
    const float* x     = (const float*)d_in[0];   // (16, 256, 4096) f32
    const float* embed = (const float*)d_in[1];   // (1024, 256) f32
    float* out = (float*)d_out;

    char* ws = (char*)d_ws;
    int*   flagcnt  = (int*)(ws + WS_FLAGCNT);
    float* loss_sum = (float*)(ws + WS_LOSS);
    int*   hist     = (int*)(ws + WS_HIST);
    float* e2       = (float*)(ws + WS_E2);
    int*   qidx     = (int*)(ws + WS_QIDX);
    int*   flaglist = (int*)(ws + WS_FLAGLIST);
    unsigned char* eswz = (unsigned char*)(ws + WS_ESWZ);

    hipMemsetAsync(ws, 0, 4160, stream);  // flagcnt + loss_sum + hist

    e2_kernel<<<K_NUM / 4, 256, 0, stream>>>(embed, e2);
    prep_eswz_kernel<<<128, 256, 0, stream>>>(embed, eswz);
    argmin_mfma_kernel<<<N_TOT / 128, 256, 0, stream>>>(x, eswz, e2, qidx, flagcnt, flaglist);
    cleanup_kernel<<<2048, 256, 0, stream>>>(x, embed, e2, flagcnt, flaglist, qidx);
    gather_kernel<<<dim3(N_TOT / 256, 4), 256, 0, stream>>>(x, embed, qidx, out, loss_sum, hist);
    finalize_kernel<<<1, 256, 0, stream>>>(hist, loss_sum, out);
}